// Round 1
// baseline (497.211 us; speedup 1.0000x reference)
//
#include <hip/hip_runtime.h>
#include <math.h>

typedef unsigned short u16;
typedef unsigned int u32;
typedef __attribute__((ext_vector_type(8))) short short8;
typedef __attribute__((ext_vector_type(4))) float f32x4;

#define B_ 8
#define S_ 2048
#define D_ 2048
#define E_ 8
#define H_ 16
#define DH_ 128
#define RLEN 4194304   // S_*D_ per batch sample (route length)
#define NCHUNK 512
#define ST 64          // s-tile rows in mlp kernel
#define GBK 32         // K-step of final GEMM

static __device__ __forceinline__ u16 f2bf(float f) {
    union { float f; u32 u; } v; v.f = f;
    u32 r = v.u + 0x7fffu + ((v.u >> 16) & 1u);
    return (u16)(r >> 16);
}
static __device__ __forceinline__ float bf2f(u16 u) {
    union { u32 u; float f; } v; v.u = ((u32)u) << 16;
    return v.f;
}

typedef const __attribute__((address_space(1))) u32* gas1_t;
typedef __attribute__((address_space(3))) u32* las3_t;
static __device__ __forceinline__ void gload_lds16(const void* g, void* l) {
    __builtin_amdgcn_global_load_lds((gas1_t)g, (las3_t)l, 16, 0, 0);
}

// ---------------- Kernel 1: router partial dots --------------------------
// Each block owns one contiguous i-chunk and accumulates all 64 (b,e) dots,
// so x and switch_w are each read exactly once (268 MB total).
__global__ __launch_bounds__(256) void router_partial(const float* __restrict__ x,
                                                      const float* __restrict__ sw,
                                                      float* __restrict__ part) {
    int c = blockIdx.x;
    int t = threadIdx.x;
    const int chunk = RLEN / NCHUNK;        // 8192
    int base = c * chunk;
    float acc[8][8];
#pragma unroll
    for (int b = 0; b < 8; b++)
#pragma unroll
        for (int e = 0; e < 8; e++) acc[b][e] = 0.f;

    for (int it = 0; it < chunk / (256 * 4); ++it) {   // 8 iterations
        int i = base + (it * 256 + t) * 4;
        float4 xv[8], sv[8];
#pragma unroll
        for (int b = 0; b < 8; b++) xv[b] = *(const float4*)&x[(size_t)b * RLEN + i];
#pragma unroll
        for (int e = 0; e < 8; e++) sv[e] = *(const float4*)&sw[(size_t)e * RLEN + i];
#pragma unroll
        for (int b = 0; b < 8; b++)
#pragma unroll
            for (int e = 0; e < 8; e++)
                acc[b][e] += xv[b].x * sv[e].x + xv[b].y * sv[e].y +
                             xv[b].z * sv[e].z + xv[b].w * sv[e].w;
    }

    __shared__ float red[4][64];
    int lane = t & 63, wv = t >> 6;
#pragma unroll
    for (int q = 0; q < 64; q++) {
        float v = acc[q >> 3][q & 7];
#pragma unroll
        for (int m = 32; m >= 1; m >>= 1) v += __shfl_xor(v, m, 64);
        if (lane == 0) red[wv][q] = v;
    }
    __syncthreads();
    if (t < 64) {
        float s = red[0][t] + red[1][t] + red[2][t] + red[3][t];
        part[(size_t)t * NCHUNK + c] = s;
    }
}

// ---------------- Kernel 2: reduce + softmax + top-2 ---------------------
__global__ __launch_bounds__(64) void router_finish(const float* __restrict__ part,
                                                    const float* __restrict__ swb,
                                                    float* __restrict__ gate,
                                                    int* __restrict__ idx) {
    int t = threadIdx.x;
    __shared__ float lg[64];
    float s = 0.f;
    for (int c = 0; c < NCHUNK; c++) s += part[(size_t)t * NCHUNK + c];
    lg[t] = s + swb[t & 7];
    __syncthreads();
    if (t < 8) {
        int b = t;
        float m = -1e30f;
        for (int e = 0; e < 8; e++) m = fmaxf(m, lg[b * 8 + e]);
        float p[8]; float sum = 0.f;
        for (int e = 0; e < 8; e++) { p[e] = expf(lg[b * 8 + e] - m); sum += p[e]; }
        for (int e = 0; e < 8; e++) p[e] /= sum;
        int i1 = 0; float v1 = p[0];
        for (int e = 1; e < 8; e++) if (p[e] > v1) { v1 = p[e]; i1 = e; }
        int i2 = -1; float v2 = -1.f;
        for (int e = 0; e < 8; e++) if (e != i1 && p[e] > v2) { v2 = p[e]; i2 = e; }
        gate[b * 2 + 0] = v1; gate[b * 2 + 1] = v2;
        idx[b * 2 + 0] = i1;  idx[b * 2 + 1] = i2;
    }
}

// ---------------- Kernel 3: w3 -> bf16 ------------------------------------
__global__ __launch_bounds__(256) void convert_w3(const float* __restrict__ w3,
                                                  u16* __restrict__ w3b) {
    size_t i = ((size_t)blockIdx.x * 256 + threadIdx.x) * 4;
    float4 v = *(const float4*)&w3[i];
    u16* d = &w3b[i];
    d[0] = f2bf(v.x); d[1] = f2bf(v.y); d[2] = f2bf(v.z); d[3] = f2bf(v.w);
}

// ---------------- Kernel 4: per-(b,head,s-tile) expert MLP ----------------
// y[b,s,h*128+d] = x + sum_k gate_k * (GELU(x@w1[e]^T + b1) @ w2[e]^T + b2)
__global__ __launch_bounds__(256) void mlp_kernel(const float* __restrict__ x,
                                                  const float* __restrict__ w1,
                                                  const float* __restrict__ b1,
                                                  const float* __restrict__ w2,
                                                  const float* __restrict__ b2,
                                                  const float* __restrict__ gate,
                                                  const int* __restrict__ idx,
                                                  u16* __restrict__ y) {
    __shared__ __align__(16) u16 xs[ST * 128];
    __shared__ __align__(16) u16 wbuf[128 * 128];
    __shared__ __align__(16) u16 hbuf[ST * 128];
    int t = threadIdx.x;
    int lane = t & 63, wv = t >> 6;
    int stile = blockIdx.x, h = blockIdx.y, b = blockIdx.z;
    int s0 = stile * ST;
    const float* xsrc = x + ((size_t)b * S_ + s0) * D_ + h * DH_;

    // stage x-tile (fp32 -> bf16, XOR-swizzled columns: col ^ ((row&7)<<3))
#pragma unroll
    for (int p = 0; p < 8; p++) {
        int row = p * 8 + (t >> 5);
        int col = (t & 31) * 4;
        float4 v = *(const float4*)&xsrc[(size_t)row * D_ + col];
        int sc = col ^ ((row & 7) << 3);
        u16* dst = &xs[row * 128 + sc];
        dst[0] = f2bf(v.x); dst[1] = f2bf(v.y); dst[2] = f2bf(v.z); dst[3] = f2bf(v.w);
    }

    f32x4 z4 = {0.f, 0.f, 0.f, 0.f};
    f32x4 oacc[8];
#pragma unroll
    for (int nt = 0; nt < 8; nt++) oacc[nt] = z4;

    for (int k = 0; k < 2; k++) {
        int e = idx[b * 2 + k];
        float g = gate[b * 2 + k];
        __syncthreads();   // protect wbuf/xs before (re)staging
        {
            const float* wsrc = w1 + (size_t)e * 16384;
#pragma unroll
            for (int p = 0; p < 16; p++) {
                int row = p * 8 + (t >> 5);
                int col = (t & 31) * 4;
                float4 v = *(const float4*)&wsrc[row * 128 + col];
                int sc = col ^ ((row & 7) << 3);
                u16* dst = &wbuf[row * 128 + sc];
                dst[0] = f2bf(v.x); dst[1] = f2bf(v.y); dst[2] = f2bf(v.z); dst[3] = f2bf(v.w);
            }
        }
        __syncthreads();

        // GEMM1: h = xs @ w1^T   (wave wv owns rows [wv*16, wv*16+16))
        f32x4 acc1[8];
#pragma unroll
        for (int nt = 0; nt < 8; nt++) acc1[nt] = z4;
#pragma unroll
        for (int kb = 0; kb < 4; kb++) {
            int koff = kb * 32 + (lane >> 4) * 8;
            int arow = wv * 16 + (lane & 15);
            short8 a = *(const short8*)&xs[arow * 128 + (koff ^ ((arow & 7) << 3))];
#pragma unroll
            for (int nt = 0; nt < 8; nt++) {
                int brow = nt * 16 + (lane & 15);
                short8 bb = *(const short8*)&wbuf[brow * 128 + (koff ^ ((brow & 7) << 3))];
                acc1[nt] = __builtin_amdgcn_mfma_f32_16x16x32_bf16(a, bb, acc1[nt], 0, 0, 0);
            }
        }
        // bias + exact GELU -> hbuf (bf16, swizzled)
#pragma unroll
        for (int nt = 0; nt < 8; nt++) {
            int fcol = nt * 16 + (lane & 15);
            float bias = b1[e * 128 + fcol];
#pragma unroll
            for (int j = 0; j < 4; j++) {
                int srow = wv * 16 + (lane >> 4) * 4 + j;
                float v = acc1[nt][j] + bias;
                v = 0.5f * v * (1.0f + erff(v * 0.70710678118654752f));
                hbuf[srow * 128 + (fcol ^ ((srow & 7) << 3))] = f2bf(v);
            }
        }
        __syncthreads();
        {
            const float* wsrc = w2 + (size_t)e * 16384;
#pragma unroll
            for (int p = 0; p < 16; p++) {
                int row = p * 8 + (t >> 5);
                int col = (t & 31) * 4;
                float4 v = *(const float4*)&wsrc[row * 128 + col];
                int sc = col ^ ((row & 7) << 3);
                u16* dst = &wbuf[row * 128 + sc];
                dst[0] = f2bf(v.x); dst[1] = f2bf(v.y); dst[2] = f2bf(v.z); dst[3] = f2bf(v.w);
            }
        }
        __syncthreads();

        // GEMM2: o = h @ w2^T, gate-weighted accumulate
        f32x4 acc2[8];
#pragma unroll
        for (int nt = 0; nt < 8; nt++) acc2[nt] = z4;
#pragma unroll
        for (int kb = 0; kb < 4; kb++) {
            int koff = kb * 32 + (lane >> 4) * 8;
            int arow = wv * 16 + (lane & 15);
            short8 a = *(const short8*)&hbuf[arow * 128 + (koff ^ ((arow & 7) << 3))];
#pragma unroll
            for (int nt = 0; nt < 8; nt++) {
                int brow = nt * 16 + (lane & 15);
                short8 bb = *(const short8*)&wbuf[brow * 128 + (koff ^ ((brow & 7) << 3))];
                acc2[nt] = __builtin_amdgcn_mfma_f32_16x16x32_bf16(a, bb, acc2[nt], 0, 0, 0);
            }
        }
#pragma unroll
        for (int nt = 0; nt < 8; nt++) {
            int dcol = nt * 16 + (lane & 15);
            float b2v = b2[e * 128 + dcol];
#pragma unroll
            for (int j = 0; j < 4; j++)
                oacc[nt][j] += g * (acc2[nt][j] + b2v);
        }
    }

    // y = x + o  (bf16)
    u16* ydst = y + ((size_t)b * S_ + s0) * D_ + h * DH_;
#pragma unroll
    for (int nt = 0; nt < 8; nt++) {
        int dcol = nt * 16 + (lane & 15);
#pragma unroll
        for (int j = 0; j < 4; j++) {
            int srow = wv * 16 + (lane >> 4) * 4 + j;
            float xres = bf2f(xs[srow * 128 + (dcol ^ ((srow & 7) << 3))]);
            ydst[(size_t)srow * D_ + dcol] = f2bf(oacc[nt][j] + xres);
        }
    }
}

// ---------------- Kernel 5: out = y @ w3^T + b3  (m97-style) --------------
__global__ __launch_bounds__(256) void final_gemm(const u16* __restrict__ ya,
                                                  const u16* __restrict__ wb,
                                                  const float* __restrict__ b3,
                                                  float* __restrict__ out) {
    __shared__ __align__(16) u16 As[128 * GBK];
    __shared__ __align__(16) u16 Bs[128 * GBK];
    int t = threadIdx.x;
    int lane = t & 63;
    int wv = t >> 6;
    int wr = wv >> 1, wc = wv & 1;
    int row0 = blockIdx.y * 128;
    int col0 = blockIdx.x * 128;

    f32x4 z4 = {0.f, 0.f, 0.f, 0.f};
    f32x4 acc[4][4];
#pragma unroll
    for (int mt = 0; mt < 4; mt++)
#pragma unroll
        for (int nt = 0; nt < 4; nt++) acc[mt][nt] = z4;

    int elem0 = t * 8;
    int r0 = elem0 >> 5, c0 = elem0 & 31;
    int elem1 = 2048 + t * 8;
    int r1 = elem1 >> 5, c1 = elem1 & 31;

    for (int kt = 0; kt < D_ / GBK; ++kt) {
        int k0 = kt * GBK;
        gload_lds16(ya + (size_t)(row0 + r0) * D_ + k0 + c0, As + elem0);
        gload_lds16(ya + (size_t)(row0 + r1) * D_ + k0 + c1, As + elem1);
        gload_lds16(wb + (size_t)(col0 + r0) * D_ + k0 + c0, Bs + elem0);
        gload_lds16(wb + (size_t)(col0 + r1) * D_ + k0 + c1, Bs + elem1);
        __syncthreads();

        int koff = (lane >> 4) * 8;
        short8 a[4], bb[4];
#pragma unroll
        for (int mt = 0; mt < 4; mt++)
            a[mt] = *(const short8*)&As[(wr * 64 + mt * 16 + (lane & 15)) * GBK + koff];
#pragma unroll
        for (int nt = 0; nt < 4; nt++)
            bb[nt] = *(const short8*)&Bs[(wc * 64 + nt * 16 + (lane & 15)) * GBK + koff];
#pragma unroll
        for (int mt = 0; mt < 4; mt++)
#pragma unroll
            for (int nt = 0; nt < 4; nt++)
                acc[mt][nt] = __builtin_amdgcn_mfma_f32_16x16x32_bf16(a[mt], bb[nt], acc[mt][nt], 0, 0, 0);
        __syncthreads();
    }

#pragma unroll
    for (int mt = 0; mt < 4; mt++)
#pragma unroll
        for (int nt = 0; nt < 4; nt++) {
            int col = col0 + wc * 64 + nt * 16 + (lane & 15);
            float bias = b3[col];
#pragma unroll
            for (int j = 0; j < 4; j++) {
                int row = row0 + wr * 64 + mt * 16 + (lane >> 4) * 4 + j;
                out[(size_t)row * D_ + col] = acc[mt][nt][j] + bias;
            }
        }
}

// ---------------------------------------------------------------------------
extern "C" void kernel_launch(void* const* d_in, const int* in_sizes, int n_in,
                              void* d_out, int out_size, void* d_ws, size_t ws_size,
                              hipStream_t stream) {
    const float* x   = (const float*)d_in[0];
    const float* sw  = (const float*)d_in[1];
    const float* swb = (const float*)d_in[2];
    const float* w1  = (const float*)d_in[3];
    const float* b1  = (const float*)d_in[4];
    const float* w2  = (const float*)d_in[5];
    const float* b2  = (const float*)d_in[6];
    const float* w3  = (const float*)d_in[7];
    const float* b3  = (const float*)d_in[8];
    float* out = (float*)d_out;

    char* ws = (char*)d_ws;
    float* part  = (float*)(ws + 0);                       // 64*512*4 = 128 KB
    float* gate  = (float*)(ws + 131072);                  // 16 floats
    int*   idx   = (int*)(ws + 131072 + 64);               // 16 ints
    u16*   y     = (u16*)(ws + (1 << 20));                 // B*S*D bf16 = 64 MB
    u16*   w3b   = (u16*)(ws + (1 << 20) + (size_t)B_ * S_ * D_ * 2);  // 8 MB

    hipLaunchKernelGGL(router_partial, dim3(NCHUNK), dim3(256), 0, stream, x, sw, part);
    hipLaunchKernelGGL(router_finish, dim3(1), dim3(64), 0, stream, part, swb, gate, idx);
    hipLaunchKernelGGL(convert_w3, dim3(D_ * D_ / 1024), dim3(256), 0, stream, w3, w3b);
    hipLaunchKernelGGL(mlp_kernel, dim3(S_ / ST, H_, B_), dim3(256), 0, stream,
                       x, w1, b1, w2, b2, gate, idx, y);
    hipLaunchKernelGGL(final_gemm, dim3(D_ / 128, (B_ * S_) / 128), dim3(256), 0, stream,
                       y, w3b, b3, out);
}

// Round 2
// 372.145 us; speedup vs baseline: 1.3361x; 1.3361x over previous
//
#include <hip/hip_runtime.h>
#include <math.h>

typedef unsigned short u16;
typedef unsigned int u32;
typedef __attribute__((ext_vector_type(8))) short short8;
typedef __attribute__((ext_vector_type(4))) float f32x4;
typedef __attribute__((ext_vector_type(4))) unsigned short ushort4v;

#define B_ 8
#define S_ 2048
#define D_ 2048
#define H_ 16
#define RLEN 4194304   // S_*D_ elems per batch sample
#define NCHUNK 512
#define GBK 32         // K-step of final GEMM

static __device__ __forceinline__ u16 f2bf(float f) {
    union { float f; u32 u; } v; v.f = f;
    u32 r = v.u + 0x7fffu + ((v.u >> 16) & 1u);
    return (u16)(r >> 16);
}
static __device__ __forceinline__ float bf2f(u16 u) {
    union { u32 u; float f; } v; v.u = ((u32)u) << 16;
    return v.f;
}

typedef const __attribute__((address_space(1))) u32* gas1_t;
typedef __attribute__((address_space(3))) u32* las3_t;
static __device__ __forceinline__ void gload_lds16(const void* g, void* l) {
    __builtin_amdgcn_global_load_lds((gas1_t)g, (las3_t)l, 16, 0, 0);
}

// ---------------- Kernel 1: router partial dots (+ fused x->bf16 swizzled) --
template<int XB>
__global__ __launch_bounds__(256) void router_partial(const float* __restrict__ x,
                                                      const float* __restrict__ sw,
                                                      float* __restrict__ part,
                                                      u16* __restrict__ xb) {
    int c = blockIdx.x;
    int t = threadIdx.x;
    const int chunk = RLEN / NCHUNK;        // 8192
    int base = c * chunk;
    float acc[8][8];
#pragma unroll
    for (int b = 0; b < 8; b++)
#pragma unroll
        for (int e = 0; e < 8; e++) acc[b][e] = 0.f;

    for (int it = 0; it < chunk / (256 * 4); ++it) {   // 8 iterations
        int i = base + (it * 256 + t) * 4;
        float4 xv[8], sv[8];
#pragma unroll
        for (int b = 0; b < 8; b++) xv[b] = *(const float4*)&x[(size_t)b * RLEN + i];
#pragma unroll
        for (int e = 0; e < 8; e++) sv[e] = *(const float4*)&sw[(size_t)e * RLEN + i];
        if (XB) {
            // store bf16 x, pre-swizzled within each 128-elem row:
            // group(col>>3) ^= (row&7); float4 is 4-aligned -> stays in one group
            int row = i >> 7, col = i & 127;
            int scol = (((col >> 3) ^ (row & 7)) << 3) | (col & 7);
#pragma unroll
            for (int b = 0; b < 8; b++) {
                ushort4v u;
                u.x = f2bf(xv[b].x); u.y = f2bf(xv[b].y);
                u.z = f2bf(xv[b].z); u.w = f2bf(xv[b].w);
                *(ushort4v*)&xb[(size_t)b * RLEN + (size_t)row * 128 + scol] = u;
            }
        }
#pragma unroll
        for (int b = 0; b < 8; b++)
#pragma unroll
            for (int e = 0; e < 8; e++)
                acc[b][e] += xv[b].x * sv[e].x + xv[b].y * sv[e].y +
                             xv[b].z * sv[e].z + xv[b].w * sv[e].w;
    }

    __shared__ float red[4][64];
    int lane = t & 63, wv = t >> 6;
#pragma unroll
    for (int q = 0; q < 64; q++) {
        float v = acc[q >> 3][q & 7];
#pragma unroll
        for (int m = 32; m >= 1; m >>= 1) v += __shfl_xor(v, m, 64);
        if (lane == 0) red[wv][q] = v;
    }
    __syncthreads();
    if (t < 64) {
        float s = red[0][t] + red[1][t] + red[2][t] + red[3][t];
        part[(size_t)t * NCHUNK + c] = s;
    }
}

// ---------------- Kernel 2: reduce + softmax + top-2 + combined b2 bias ----
__global__ __launch_bounds__(128) void router_finish(const float* __restrict__ part,
                                                     const float* __restrict__ swb,
                                                     const float* __restrict__ b2,
                                                     float* __restrict__ gate,
                                                     int* __restrict__ idx,
                                                     float* __restrict__ bc) {
    int t = threadIdx.x;
    __shared__ float lg[64];
    __shared__ float sg[16];
    __shared__ int   si[16];
    if (t < 64) {
        float s = 0.f;
        for (int c = 0; c < NCHUNK; c++) s += part[(size_t)t * NCHUNK + c];
        lg[t] = s + swb[t & 7];
    }
    __syncthreads();
    if (t < 8) {
        int b = t;
        float m = -1e30f;
        for (int e = 0; e < 8; e++) m = fmaxf(m, lg[b * 8 + e]);
        float p[8]; float sum = 0.f;
        for (int e = 0; e < 8; e++) { p[e] = expf(lg[b * 8 + e] - m); sum += p[e]; }
        for (int e = 0; e < 8; e++) p[e] /= sum;
        int i1 = 0; float v1 = p[0];
        for (int e = 1; e < 8; e++) if (p[e] > v1) { v1 = p[e]; i1 = e; }
        int i2 = -1; float v2 = -1.f;
        for (int e = 0; e < 8; e++) if (e != i1 && p[e] > v2) { v2 = p[e]; i2 = e; }
        gate[b * 2 + 0] = v1; gate[b * 2 + 1] = v2;
        idx[b * 2 + 0] = i1;  idx[b * 2 + 1] = i2;
        sg[b * 2] = v1; sg[b * 2 + 1] = v2;
        si[b * 2] = i1; si[b * 2 + 1] = i2;
    }
    __syncthreads();
    // bc[b][d] = g0*b2[e0][d] + g1*b2[e1][d]
    for (int b = 0; b < 8; b++)
        bc[b * 128 + t] = sg[b * 2] * b2[si[b * 2] * 128 + t] +
                          sg[b * 2 + 1] * b2[si[b * 2 + 1] * 128 + t];
}

// ---------------- Kernel 3a: w1/w2 -> bf16 (w1 swizzled) -------------------
__global__ __launch_bounds__(256) void convert_w12(const float* __restrict__ w1,
                                                   const float* __restrict__ w2,
                                                   u16* __restrict__ w1b,
                                                   u16* __restrict__ w2b) {
    int i4 = (blockIdx.x * 256 + threadIdx.x) * 4;
    if (i4 < 131072) {
        int k = i4 & 127, f = (i4 >> 7) & 127;
        float4 v = *(const float4*)&w1[i4];
        int sc = ((((k >> 3) ^ (f & 7)) << 3) | (k & 7));
        ushort4v u;
        u.x = f2bf(v.x); u.y = f2bf(v.y); u.z = f2bf(v.z); u.w = f2bf(v.w);
        *(ushort4v*)&w1b[(i4 & ~127) + sc] = u;
    } else {
        int j = i4 - 131072;
        float4 v = *(const float4*)&w2[j];
        ushort4v u;
        u.x = f2bf(v.x); u.y = f2bf(v.y); u.z = f2bf(v.z); u.w = f2bf(v.w);
        *(ushort4v*)&w2b[j] = u;
    }
}

// ---------------- Kernel 3b: w3 -> bf16 ------------------------------------
__global__ __launch_bounds__(256) void convert_w3(const float* __restrict__ w3,
                                                  u16* __restrict__ w3b) {
    size_t i = ((size_t)blockIdx.x * 256 + threadIdx.x) * 4;
    float4 v = *(const float4*)&w3[i];
    u16* d = &w3b[i];
    d[0] = f2bf(v.x); d[1] = f2bf(v.y); d[2] = f2bf(v.z); d[3] = f2bf(v.w);
}

// ---------------- Kernel 4: expert MLP, weights resident, 512-row blocks ---
// x[b] viewed as [32768 rows x 128] (row = s*16+h). Per block: stage W1 for
// both selected experts (256x128 bf16, swizzled LDS), W2' frags in registers,
// loop 8 x 64-row tiles: GEMM1 -> GELU*gate -> hbuf -> GEMM2 -> y = x + o.
template<int XB>
__global__ __launch_bounds__(512, 2) void mlp_kernel(const void* __restrict__ xsrc_,
                                                     const u16* __restrict__ w1b,
                                                     const u16* __restrict__ w2b,
                                                     const float* __restrict__ b1,
                                                     const float* __restrict__ gate,
                                                     const int* __restrict__ idx,
                                                     const float* __restrict__ bc,
                                                     u16* __restrict__ y) {
    __shared__ __align__(16) u16 w1s[256 * 128];   // 64 KB
    __shared__ __align__(16) u16 xs[2][64 * 128];  // 32 KB (dbuf)
    __shared__ __align__(16) u16 hb[64 * 256];     // 32 KB
    const int t = threadIdx.x, lane = t & 63, w = t >> 6;
    const int wr = w >> 2, wq = w & 3;
    const int b = blockIdx.y, grp = blockIdx.x;
    const size_t xbase = (size_t)b * RLEN;
    const size_t gbase = xbase + (size_t)grp * 65536;   // elem offset of group
    const int e0 = idx[b * 2], e1 = idx[b * 2 + 1];
    const int slot = wq >> 1;
    const float gw = gate[b * 2 + slot];
    const float* b1p = b1 + (slot ? e1 : e0) * 128;

    float b1v[4];
#pragma unroll
    for (int nt = 0; nt < 4; nt++)
        b1v[nt] = b1p[(wq & 1) * 64 + nt * 16 + (lane & 15)];
    float bcv[2];
#pragma unroll
    for (int n = 0; n < 2; n++)
        bcv[n] = bc[b * 128 + wq * 32 + n * 16 + (lane & 15)];

    // W2' fragments in registers: wave owns d-block wq*32..+32 (2 nt), K=256 f
    short8 w2f[2][8];
#pragma unroll
    for (int n = 0; n < 2; n++) {
        int d = wq * 32 + n * 16 + (lane & 15);
#pragma unroll
        for (int kb = 0; kb < 8; kb++) {
            int e = (kb >= 4) ? e1 : e0;
            int f = (kb & 3) * 32 + (lane >> 4) * 8;
            w2f[n][kb] = *(const short8*)&w2b[((size_t)(e * 128 + d)) * 128 + f];
        }
    }

    // stage W1 for both experts (global pre-swizzled -> linear LDS copy)
#pragma unroll
    for (int p = 0; p < 8; p++) {
        int elem = p * 4096 + t * 8;
        int frow = elem >> 7, col = elem & 127;
        int e = (frow >= 128) ? e1 : e0;
        gload_lds16(w1b + ((size_t)(e * 128 + (frow & 127))) * 128 + col,
                    (char*)w1s + elem * 2);
    }
    // stage x tile 0
    if (XB) {
        const u16* xbp = (const u16*)xsrc_;
#pragma unroll
        for (int p = 0; p < 2; p++) {
            int elem = p * 4096 + t * 8;
            gload_lds16(xbp + gbase + elem, (char*)&xs[0][0] + elem * 2);
        }
        asm volatile("s_waitcnt vmcnt(0)" ::: "memory");
    } else {
        const float* xf = (const float*)xsrc_;
#pragma unroll
        for (int p = 0; p < 4; p++) {
            int elem = p * 2048 + t * 4;
            int row = elem >> 7, col = elem & 127;
            float4 v = *(const float4*)&xf[gbase + elem];
            ushort4v u;
            u.x = f2bf(v.x); u.y = f2bf(v.y); u.z = f2bf(v.z); u.w = f2bf(v.w);
            *(ushort4v*)((char*)&xs[0][0] + row * 256 +
                         (((col >> 3) ^ (row & 7)) << 4) + (col & 7) * 2) = u;
        }
        asm volatile("s_waitcnt vmcnt(0) lgkmcnt(0)" ::: "memory");
    }
    __builtin_amdgcn_s_barrier();

    for (int tt = 0; tt < 8; ++tt) {
        const u16* xc = &xs[tt & 1][0];
        u16* xn = &xs[(tt + 1) & 1][0];
        float4 pre[4];
        if (tt < 7) {   // prefetch next x tile into the other buffer
            if (XB) {
                const u16* xbp = (const u16*)xsrc_;
#pragma unroll
                for (int p = 0; p < 2; p++) {
                    int elem = p * 4096 + t * 8;
                    gload_lds16(xbp + gbase + (tt + 1) * 8192 + elem,
                                (char*)xn + elem * 2);
                }
            } else {
                const float* xf = (const float*)xsrc_;
#pragma unroll
                for (int p = 0; p < 4; p++) {
                    int elem = p * 2048 + t * 4;
                    pre[p] = *(const float4*)&xf[gbase + (tt + 1) * 8192 + elem];
                }
            }
        }

        // GEMM1: h[64 x 256] = x_tile @ W1'^T   (wave: rows wr*32..+32, f wq*64..+64)
        f32x4 acc1[2][4];
#pragma unroll
        for (int mt = 0; mt < 2; mt++)
#pragma unroll
            for (int nt = 0; nt < 4; nt++) acc1[mt][nt] = (f32x4){0.f, 0.f, 0.f, 0.f};
#pragma unroll
        for (int kb = 0; kb < 4; kb++) {
            int kg = kb * 4 + (lane >> 4);
            int r0 = wr * 32 + (lane & 15);
            int r1 = r0 + 16;
            short8 a0 = *(const short8*)&xc[r0 * 128 + ((kg ^ (r0 & 7)) << 3)];
            short8 a1 = *(const short8*)&xc[r1 * 128 + ((kg ^ (r1 & 7)) << 3)];
#pragma unroll
            for (int nt = 0; nt < 4; nt++) {
                int fr = wq * 64 + nt * 16 + (lane & 15);
                short8 bb = *(const short8*)&w1s[fr * 128 + ((kg ^ (fr & 7)) << 3)];
                acc1[0][nt] = __builtin_amdgcn_mfma_f32_16x16x32_bf16(a0, bb, acc1[0][nt], 0, 0, 0);
                acc1[1][nt] = __builtin_amdgcn_mfma_f32_16x16x32_bf16(a1, bb, acc1[1][nt], 0, 0, 0);
            }
        }

        // bias + exact GELU, gate folded, -> hbuf (swizzled)
#pragma unroll
        for (int mt = 0; mt < 2; mt++)
#pragma unroll
            for (int nt = 0; nt < 4; nt++) {
                int fcol = wq * 64 + nt * 16 + (lane & 15);
#pragma unroll
                for (int j = 0; j < 4; j++) {
                    int row = wr * 32 + mt * 16 + (lane >> 4) * 4 + j;
                    float v = acc1[mt][nt][j] + b1v[nt];
                    v = 0.5f * v * (1.0f + erff(v * 0.70710678118654752f)) * gw;
                    hb[row * 256 + ((((fcol >> 3) ^ (row & 7)) << 3) | (fcol & 7))] = f2bf(v);
                }
            }
        asm volatile("s_waitcnt lgkmcnt(0)" ::: "memory");
        __builtin_amdgcn_s_barrier();

        if (!XB && tt < 7) {   // T14: write prefetched fp32 tile now
#pragma unroll
            for (int p = 0; p < 4; p++) {
                int elem = p * 2048 + t * 4;
                int row = elem >> 7, col = elem & 127;
                ushort4v u;
                u.x = f2bf(pre[p].x); u.y = f2bf(pre[p].y);
                u.z = f2bf(pre[p].z); u.w = f2bf(pre[p].w);
                *(ushort4v*)((char*)xn + row * 256 +
                             (((col >> 3) ^ (row & 7)) << 4) + (col & 7) * 2) = u;
            }
        }

        // GEMM2: o[64 x 128] = h @ W2'^T   (wave: rows wr*32..+32, d wq*32..+32)
        f32x4 acc2[2][2];
#pragma unroll
        for (int mt = 0; mt < 2; mt++)
#pragma unroll
            for (int n = 0; n < 2; n++) acc2[mt][n] = (f32x4){0.f, 0.f, 0.f, 0.f};
#pragma unroll
        for (int kb = 0; kb < 8; kb++) {
            int fg = kb * 4 + (lane >> 4);
            int r0 = wr * 32 + (lane & 15);
            int r1 = r0 + 16;
            short8 a0 = *(const short8*)&hb[r0 * 256 + ((fg ^ (r0 & 7)) << 3)];
            short8 a1 = *(const short8*)&hb[r1 * 256 + ((fg ^ (r1 & 7)) << 3)];
            acc2[0][0] = __builtin_amdgcn_mfma_f32_16x16x32_bf16(a0, w2f[0][kb], acc2[0][0], 0, 0, 0);
            acc2[0][1] = __builtin_amdgcn_mfma_f32_16x16x32_bf16(a0, w2f[1][kb], acc2[0][1], 0, 0, 0);
            acc2[1][0] = __builtin_amdgcn_mfma_f32_16x16x32_bf16(a1, w2f[0][kb], acc2[1][0], 0, 0, 0);
            acc2[1][1] = __builtin_amdgcn_mfma_f32_16x16x32_bf16(a1, w2f[1][kb], acc2[1][1], 0, 0, 0);
        }

        // epilogue: y = x + o + bc   (16 u16 stores/lane)
        u16* yb = y + xbase + (size_t)grp * 65536 + tt * 8192;
#pragma unroll
        for (int mt = 0; mt < 2; mt++)
#pragma unroll
            for (int n = 0; n < 2; n++) {
                int d = wq * 32 + n * 16 + (lane & 15);
#pragma unroll
                for (int j = 0; j < 4; j++) {
                    int row = wr * 32 + mt * 16 + (lane >> 4) * 4 + j;
                    float xr = bf2f(xc[row * 128 + ((((d >> 3) ^ (row & 7)) << 3) | (d & 7))]);
                    yb[row * 128 + d] = f2bf(acc2[mt][n][j] + bcv[n] + xr);
                }
            }
        asm volatile("s_waitcnt lgkmcnt(0)" ::: "memory");
        if (XB && tt < 7) asm volatile("s_waitcnt vmcnt(16)" ::: "memory");
        __builtin_amdgcn_s_barrier();
    }
}

// ---------------- Kernel 5: out = y @ w3^T + b3  (m97-style) --------------
__global__ __launch_bounds__(256) void final_gemm(const u16* __restrict__ ya,
                                                  const u16* __restrict__ wb,
                                                  const float* __restrict__ b3,
                                                  float* __restrict__ out) {
    __shared__ __align__(16) u16 As[128 * GBK];
    __shared__ __align__(16) u16 Bs[128 * GBK];
    int t = threadIdx.x;
    int lane = t & 63;
    int wv = t >> 6;
    int wr = wv >> 1, wc = wv & 1;
    int row0 = blockIdx.y * 128;
    int col0 = blockIdx.x * 128;

    f32x4 z4 = {0.f, 0.f, 0.f, 0.f};
    f32x4 acc[4][4];
#pragma unroll
    for (int mt = 0; mt < 4; mt++)
#pragma unroll
        for (int nt = 0; nt < 4; nt++) acc[mt][nt] = z4;

    int elem0 = t * 8;
    int r0 = elem0 >> 5, c0 = elem0 & 31;
    int elem1 = 2048 + t * 8;
    int r1 = elem1 >> 5, c1 = elem1 & 31;

    for (int kt = 0; kt < D_ / GBK; ++kt) {
        int k0 = kt * GBK;
        gload_lds16(ya + (size_t)(row0 + r0) * D_ + k0 + c0, As + elem0);
        gload_lds16(ya + (size_t)(row0 + r1) * D_ + k0 + c1, As + elem1);
        gload_lds16(wb + (size_t)(col0 + r0) * D_ + k0 + c0, Bs + elem0);
        gload_lds16(wb + (size_t)(col0 + r1) * D_ + k0 + c1, Bs + elem1);
        __syncthreads();

        int koff = (lane >> 4) * 8;
        short8 a[4], bb[4];
#pragma unroll
        for (int mt = 0; mt < 4; mt++)
            a[mt] = *(const short8*)&As[(wr * 64 + mt * 16 + (lane & 15)) * GBK + koff];
#pragma unroll
        for (int nt = 0; nt < 4; nt++)
            bb[nt] = *(const short8*)&Bs[(wc * 64 + nt * 16 + (lane & 15)) * GBK + koff];
#pragma unroll
        for (int mt = 0; mt < 4; mt++)
#pragma unroll
            for (int nt = 0; nt < 4; nt++)
                acc[mt][nt] = __builtin_amdgcn_mfma_f32_16x16x32_bf16(a[mt], bb[nt], acc[mt][nt], 0, 0, 0);
        __syncthreads();
    }

#pragma unroll
    for (int mt = 0; mt < 4; mt++)
#pragma unroll
        for (int nt = 0; nt < 4; nt++) {
            int col = col0 + wc * 64 + nt * 16 + (lane & 15);
            float bias = b3[col];
#pragma unroll
            for (int j = 0; j < 4; j++) {
                int row = row0 + wr * 64 + mt * 16 + (lane >> 4) * 4 + j;
                out[(size_t)row * D_ + col] = acc[mt][nt][j] + bias;
            }
        }
}

// ---------------------------------------------------------------------------
extern "C" void kernel_launch(void* const* d_in, const int* in_sizes, int n_in,
                              void* d_out, int out_size, void* d_ws, size_t ws_size,
                              hipStream_t stream) {
    const float* x   = (const float*)d_in[0];
    const float* sw  = (const float*)d_in[1];
    const float* swb = (const float*)d_in[2];
    const float* w1  = (const float*)d_in[3];
    const float* b1  = (const float*)d_in[4];
    const float* w2  = (const float*)d_in[5];
    const float* b2  = (const float*)d_in[6];
    const float* w3  = (const float*)d_in[7];
    const float* b3  = (const float*)d_in[8];
    float* out = (float*)d_out;

    char* ws = (char*)d_ws;
    float* part = (float*)(ws + 0);                 // 128 KB
    float* gate = (float*)(ws + 131072);            // 64 B
    int*   idx  = (int*)(ws + 131136);              // 64 B
    float* bc   = (float*)(ws + 131200);            // 4 KB
    u16*   w1b  = (u16*)(ws + 262144);              // 256 KB (swizzled)
    u16*   w2b  = (u16*)(ws + 524288);              // 256 KB
    u16*   w3b  = (u16*)(ws + 786432);              // 8 MB
    u16*   y    = (u16*)(ws + 9175040);             // 64 MB
    u16*   xb   = (u16*)(ws + 76283904);            // 64 MB (swizzled bf16 x)
    const size_t need_xb = 143392768;
    const bool xbmode = ws_size >= need_xb;

    if (xbmode)
        hipLaunchKernelGGL((router_partial<1>), dim3(NCHUNK), dim3(256), 0, stream, x, sw, part, xb);
    else
        hipLaunchKernelGGL((router_partial<0>), dim3(NCHUNK), dim3(256), 0, stream, x, sw, part, xb);
    hipLaunchKernelGGL(router_finish, dim3(1), dim3(128), 0, stream, part, swb, b2, gate, idx, bc);
    hipLaunchKernelGGL(convert_w12, dim3(256), dim3(256), 0, stream, w1, w2, w1b, w2b);
    hipLaunchKernelGGL(convert_w3, dim3(D_ * D_ / 1024), dim3(256), 0, stream, w3, w3b);
    if (xbmode)
        hipLaunchKernelGGL((mlp_kernel<1>), dim3(64, 8), dim3(512), 0, stream,
                           (const void*)xb, w1b, w2b, b1, gate, idx, bc, y);
    else
        hipLaunchKernelGGL((mlp_kernel<0>), dim3(64, 8), dim3(512), 0, stream,
                           (const void*)x, w1b, w2b, b1, gate, idx, bc, y);
    hipLaunchKernelGGL(final_gemm, dim3(D_ / 128, (B_ * S_) / 128), dim3(256), 0, stream,
                       y, w3b, b3, out);
}

// Round 4
// 347.419 us; speedup vs baseline: 1.4312x; 1.0712x over previous
//
#include <hip/hip_runtime.h>
#include <math.h>

typedef unsigned short u16;
typedef unsigned int u32;
typedef __attribute__((ext_vector_type(8))) short short8;
typedef __attribute__((ext_vector_type(4))) float f32x4;
typedef __attribute__((ext_vector_type(4))) unsigned short ushort4v;

#define B_ 8
#define S_ 2048
#define D_ 2048
#define H_ 16
#define RLEN 4194304   // S_*D_ elems per batch sample
#define NCHUNK 512

static __device__ __forceinline__ u16 f2bf(float f) {
    union { float f; u32 u; } v; v.f = f;
    u32 r = v.u + 0x7fffu + ((v.u >> 16) & 1u);
    return (u16)(r >> 16);
}
static __device__ __forceinline__ float bf2f(u16 u) {
    union { u32 u; float f; } v; v.u = ((u32)u) << 16;
    return v.f;
}

typedef const __attribute__((address_space(1))) u32* gas1_t;
typedef __attribute__((address_space(3))) u32* las3_t;
static __device__ __forceinline__ void gload_lds16(const void* g, void* l) {
    __builtin_amdgcn_global_load_lds((gas1_t)g, (las3_t)l, 16, 0, 0);
}

// ---------------- Kernel 1: router partial dots (+ fused x->bf16 swizzled) --
template<int XB>
__global__ __launch_bounds__(256) void router_partial(const float* __restrict__ x,
                                                      const float* __restrict__ sw,
                                                      float* __restrict__ part,
                                                      u16* __restrict__ xb) {
    int c = blockIdx.x;
    int t = threadIdx.x;
    const int chunk = RLEN / NCHUNK;        // 8192
    int base = c * chunk;
    float acc[8][8];
#pragma unroll
    for (int b = 0; b < 8; b++)
#pragma unroll
        for (int e = 0; e < 8; e++) acc[b][e] = 0.f;

    for (int it = 0; it < chunk / (256 * 4); ++it) {   // 8 iterations
        int i = base + (it * 256 + t) * 4;
        float4 xv[8], sv[8];
#pragma unroll
        for (int b = 0; b < 8; b++) xv[b] = *(const float4*)&x[(size_t)b * RLEN + i];
#pragma unroll
        for (int e = 0; e < 8; e++) sv[e] = *(const float4*)&sw[(size_t)e * RLEN + i];
        if (XB) {
            int row = i >> 7, col = i & 127;
            int scol = (((col >> 3) ^ (row & 7)) << 3) | (col & 7);
#pragma unroll
            for (int b = 0; b < 8; b++) {
                ushort4v u;
                u.x = f2bf(xv[b].x); u.y = f2bf(xv[b].y);
                u.z = f2bf(xv[b].z); u.w = f2bf(xv[b].w);
                *(ushort4v*)&xb[(size_t)b * RLEN + (size_t)row * 128 + scol] = u;
            }
        }
#pragma unroll
        for (int b = 0; b < 8; b++)
#pragma unroll
            for (int e = 0; e < 8; e++)
                acc[b][e] += xv[b].x * sv[e].x + xv[b].y * sv[e].y +
                             xv[b].z * sv[e].z + xv[b].w * sv[e].w;
    }

    __shared__ float red[4][64];
    int lane = t & 63, wv = t >> 6;
#pragma unroll
    for (int q = 0; q < 64; q++) {
        float v = acc[q >> 3][q & 7];
#pragma unroll
        for (int m = 32; m >= 1; m >>= 1) v += __shfl_xor(v, m, 64);
        if (lane == 0) red[wv][q] = v;
    }
    __syncthreads();
    if (t < 64) {
        float s = red[0][t] + red[1][t] + red[2][t] + red[3][t];
        part[(size_t)t * NCHUNK + c] = s;
    }
}

// ---------------- Kernel 2: reduce + softmax + top-2 + combined b2 bias ----
__global__ __launch_bounds__(128) void router_finish(const float* __restrict__ part,
                                                     const float* __restrict__ swb,
                                                     const float* __restrict__ b2,
                                                     float* __restrict__ gate,
                                                     int* __restrict__ idx,
                                                     float* __restrict__ bc) {
    int t = threadIdx.x;
    __shared__ float lg[64];
    __shared__ float sg[16];
    __shared__ int   si[16];
    if (t < 64) {
        float s = 0.f;
        for (int c = 0; c < NCHUNK; c++) s += part[(size_t)t * NCHUNK + c];
        lg[t] = s + swb[t & 7];
    }
    __syncthreads();
    if (t < 8) {
        int b = t;
        float m = -1e30f;
        for (int e = 0; e < 8; e++) m = fmaxf(m, lg[b * 8 + e]);
        float p[8]; float sum = 0.f;
        for (int e = 0; e < 8; e++) { p[e] = expf(lg[b * 8 + e] - m); sum += p[e]; }
        for (int e = 0; e < 8; e++) p[e] /= sum;
        int i1 = 0; float v1 = p[0];
        for (int e = 1; e < 8; e++) if (p[e] > v1) { v1 = p[e]; i1 = e; }
        int i2 = -1; float v2 = -1.f;
        for (int e = 0; e < 8; e++) if (e != i1 && p[e] > v2) { v2 = p[e]; i2 = e; }
        gate[b * 2 + 0] = v1; gate[b * 2 + 1] = v2;
        idx[b * 2 + 0] = i1;  idx[b * 2 + 1] = i2;
        sg[b * 2] = v1; sg[b * 2 + 1] = v2;
        si[b * 2] = i1; si[b * 2 + 1] = i2;
    }
    __syncthreads();
    for (int b = 0; b < 8; b++)
        bc[b * 128 + t] = sg[b * 2] * b2[si[b * 2] * 128 + t] +
                          sg[b * 2 + 1] * b2[si[b * 2 + 1] * 128 + t];
}

// ---------------- Kernel 3a: w1/w2 -> bf16 (w1 swizzled) -------------------
__global__ __launch_bounds__(256) void convert_w12(const float* __restrict__ w1,
                                                   const float* __restrict__ w2,
                                                   u16* __restrict__ w1b,
                                                   u16* __restrict__ w2b) {
    int i4 = (blockIdx.x * 256 + threadIdx.x) * 4;
    if (i4 < 131072) {
        int k = i4 & 127, f = (i4 >> 7) & 127;
        float4 v = *(const float4*)&w1[i4];
        int sc = ((((k >> 3) ^ (f & 7)) << 3) | (k & 7));
        ushort4v u;
        u.x = f2bf(v.x); u.y = f2bf(v.y); u.z = f2bf(v.z); u.w = f2bf(v.w);
        *(ushort4v*)&w1b[(i4 & ~127) + sc] = u;
    } else {
        int j = i4 - 131072;
        float4 v = *(const float4*)&w2[j];
        ushort4v u;
        u.x = f2bf(v.x); u.y = f2bf(v.y); u.z = f2bf(v.z); u.w = f2bf(v.w);
        *(ushort4v*)&w2b[j] = u;
    }
}

// ---------------- Kernel 3b: w3 -> bf16 ------------------------------------
__global__ __launch_bounds__(256) void convert_w3(const float* __restrict__ w3,
                                                  u16* __restrict__ w3b) {
    size_t i = ((size_t)blockIdx.x * 256 + threadIdx.x) * 4;
    float4 v = *(const float4*)&w3[i];
    u16* d = &w3b[i];
    d[0] = f2bf(v.x); d[1] = f2bf(v.y); d[2] = f2bf(v.z); d[3] = f2bf(v.w);
}

// ---------------- Kernel 4: expert MLP, weights resident, 512-row blocks ---
template<int XB>
__global__ __launch_bounds__(512, 2) void mlp_kernel(const void* __restrict__ xsrc_,
                                                     const u16* __restrict__ w1b,
                                                     const u16* __restrict__ w2b,
                                                     const float* __restrict__ b1,
                                                     const float* __restrict__ gate,
                                                     const int* __restrict__ idx,
                                                     const float* __restrict__ bc,
                                                     u16* __restrict__ y) {
    __shared__ __align__(16) u16 w1s[256 * 128];   // 64 KB
    __shared__ __align__(16) u16 xs[2][64 * 128];  // 32 KB (dbuf)
    __shared__ __align__(16) u16 hb[64 * 256];     // 32 KB
    const int t = threadIdx.x, lane = t & 63, w = t >> 6;
    const int wr = w >> 2, wq = w & 3;
    const int b = blockIdx.y, grp = blockIdx.x;
    const size_t xbase = (size_t)b * RLEN;
    const size_t gbase = xbase + (size_t)grp * 65536;
    const int e0 = idx[b * 2], e1 = idx[b * 2 + 1];
    const int slot = wq >> 1;
    const float gw = gate[b * 2 + slot];
    const float* b1p = b1 + (slot ? e1 : e0) * 128;

    float b1v[4];
#pragma unroll
    for (int nt = 0; nt < 4; nt++)
        b1v[nt] = b1p[(wq & 1) * 64 + nt * 16 + (lane & 15)];
    float bcv[2];
#pragma unroll
    for (int n = 0; n < 2; n++)
        bcv[n] = bc[b * 128 + wq * 32 + n * 16 + (lane & 15)];

    short8 w2f[2][8];
#pragma unroll
    for (int n = 0; n < 2; n++) {
        int d = wq * 32 + n * 16 + (lane & 15);
#pragma unroll
        for (int kb = 0; kb < 8; kb++) {
            int e = (kb >= 4) ? e1 : e0;
            int f = (kb & 3) * 32 + (lane >> 4) * 8;
            w2f[n][kb] = *(const short8*)&w2b[((size_t)(e * 128 + d)) * 128 + f];
        }
    }

#pragma unroll
    for (int p = 0; p < 8; p++) {
        int elem = p * 4096 + t * 8;
        int frow = elem >> 7, col = elem & 127;
        int e = (frow >= 128) ? e1 : e0;
        gload_lds16(w1b + ((size_t)(e * 128 + (frow & 127))) * 128 + col,
                    (char*)w1s + elem * 2);
    }
    if (XB) {
        const u16* xbp = (const u16*)xsrc_;
#pragma unroll
        for (int p = 0; p < 2; p++) {
            int elem = p * 4096 + t * 8;
            gload_lds16(xbp + gbase + elem, (char*)&xs[0][0] + elem * 2);
        }
        asm volatile("s_waitcnt vmcnt(0)" ::: "memory");
    } else {
        const float* xf = (const float*)xsrc_;
#pragma unroll
        for (int p = 0; p < 4; p++) {
            int elem = p * 2048 + t * 4;
            int row = elem >> 7, col = elem & 127;
            float4 v = *(const float4*)&xf[gbase + elem];
            ushort4v u;
            u.x = f2bf(v.x); u.y = f2bf(v.y); u.z = f2bf(v.z); u.w = f2bf(v.w);
            *(ushort4v*)((char*)&xs[0][0] + row * 256 +
                         (((col >> 3) ^ (row & 7)) << 4) + (col & 7) * 2) = u;
        }
        asm volatile("s_waitcnt vmcnt(0) lgkmcnt(0)" ::: "memory");
    }
    __builtin_amdgcn_s_barrier();

    for (int tt = 0; tt < 8; ++tt) {
        const u16* xc = &xs[tt & 1][0];
        u16* xn = &xs[(tt + 1) & 1][0];
        float4 pre[4];
        if (tt < 7) {
            if (XB) {
                const u16* xbp = (const u16*)xsrc_;
#pragma unroll
                for (int p = 0; p < 2; p++) {
                    int elem = p * 4096 + t * 8;
                    gload_lds16(xbp + gbase + (tt + 1) * 8192 + elem,
                                (char*)xn + elem * 2);
                }
            } else {
                const float* xf = (const float*)xsrc_;
#pragma unroll
                for (int p = 0; p < 4; p++) {
                    int elem = p * 2048 + t * 4;
                    pre[p] = *(const float4*)&xf[gbase + (tt + 1) * 8192 + elem];
                }
            }
        }

        f32x4 acc1[2][4];
#pragma unroll
        for (int mt = 0; mt < 2; mt++)
#pragma unroll
            for (int nt = 0; nt < 4; nt++) acc1[mt][nt] = (f32x4){0.f, 0.f, 0.f, 0.f};
#pragma unroll
        for (int kb = 0; kb < 4; kb++) {
            int kg = kb * 4 + (lane >> 4);
            int r0 = wr * 32 + (lane & 15);
            int r1 = r0 + 16;
            short8 a0 = *(const short8*)&xc[r0 * 128 + ((kg ^ (r0 & 7)) << 3)];
            short8 a1 = *(const short8*)&xc[r1 * 128 + ((kg ^ (r1 & 7)) << 3)];
#pragma unroll
            for (int nt = 0; nt < 4; nt++) {
                int fr = wq * 64 + nt * 16 + (lane & 15);
                short8 bb = *(const short8*)&w1s[fr * 128 + ((kg ^ (fr & 7)) << 3)];
                acc1[0][nt] = __builtin_amdgcn_mfma_f32_16x16x32_bf16(a0, bb, acc1[0][nt], 0, 0, 0);
                acc1[1][nt] = __builtin_amdgcn_mfma_f32_16x16x32_bf16(a1, bb, acc1[1][nt], 0, 0, 0);
            }
        }

#pragma unroll
        for (int mt = 0; mt < 2; mt++)
#pragma unroll
            for (int nt = 0; nt < 4; nt++) {
                int fcol = wq * 64 + nt * 16 + (lane & 15);
#pragma unroll
                for (int j = 0; j < 4; j++) {
                    int row = wr * 32 + mt * 16 + (lane >> 4) * 4 + j;
                    float v = acc1[mt][nt][j] + b1v[nt];
                    v = 0.5f * v * (1.0f + erff(v * 0.70710678118654752f)) * gw;
                    hb[row * 256 + ((((fcol >> 3) ^ (row & 7)) << 3) | (fcol & 7))] = f2bf(v);
                }
            }
        asm volatile("s_waitcnt lgkmcnt(0)" ::: "memory");
        __builtin_amdgcn_s_barrier();

        if (!XB && tt < 7) {
#pragma unroll
            for (int p = 0; p < 4; p++) {
                int elem = p * 2048 + t * 4;
                int row = elem >> 7, col = elem & 127;
                ushort4v u;
                u.x = f2bf(pre[p].x); u.y = f2bf(pre[p].y);
                u.z = f2bf(pre[p].z); u.w = f2bf(pre[p].w);
                *(ushort4v*)((char*)xn + row * 256 +
                             (((col >> 3) ^ (row & 7)) << 4) + (col & 7) * 2) = u;
            }
        }

        f32x4 acc2[2][2];
#pragma unroll
        for (int mt = 0; mt < 2; mt++)
#pragma unroll
            for (int n = 0; n < 2; n++) acc2[mt][n] = (f32x4){0.f, 0.f, 0.f, 0.f};
#pragma unroll
        for (int kb = 0; kb < 8; kb++) {
            int fg = kb * 4 + (lane >> 4);
            int r0 = wr * 32 + (lane & 15);
            int r1 = r0 + 16;
            short8 a0 = *(const short8*)&hb[r0 * 256 + ((fg ^ (r0 & 7)) << 3)];
            short8 a1 = *(const short8*)&hb[r1 * 256 + ((fg ^ (r1 & 7)) << 3)];
            acc2[0][0] = __builtin_amdgcn_mfma_f32_16x16x32_bf16(a0, w2f[0][kb], acc2[0][0], 0, 0, 0);
            acc2[0][1] = __builtin_amdgcn_mfma_f32_16x16x32_bf16(a0, w2f[1][kb], acc2[0][1], 0, 0, 0);
            acc2[1][0] = __builtin_amdgcn_mfma_f32_16x16x32_bf16(a1, w2f[0][kb], acc2[1][0], 0, 0, 0);
            acc2[1][1] = __builtin_amdgcn_mfma_f32_16x16x32_bf16(a1, w2f[1][kb], acc2[1][1], 0, 0, 0);
        }

        u16* yb = y + xbase + (size_t)grp * 65536 + tt * 8192;
#pragma unroll
        for (int mt = 0; mt < 2; mt++)
#pragma unroll
            for (int n = 0; n < 2; n++) {
                int d = wq * 32 + n * 16 + (lane & 15);
#pragma unroll
                for (int j = 0; j < 4; j++) {
                    int row = wr * 32 + mt * 16 + (lane >> 4) * 4 + j;
                    float xr = bf2f(xc[row * 128 + ((((d >> 3) ^ (row & 7)) << 3) | (d & 7))]);
                    yb[row * 128 + d] = f2bf(acc2[mt][n][j] + bcv[n] + xr);
                }
            }
        asm volatile("s_waitcnt lgkmcnt(0)" ::: "memory");
        if (XB && tt < 7) asm volatile("s_waitcnt vmcnt(16)" ::: "memory");
        __builtin_amdgcn_s_barrier();
    }
}

// ---------------- Kernel 5: out = y @ w3^T + b3, 256^2 4-phase -------------
// BM=BN=256, BK=64, 8 waves (2Mx4N), 128KB dynamic LDS (2 dbuf x A/B 32KB).
// Hazard-free schedule: all ds_reads of buf[cur] complete by end-P3 (sealed
// by each wave's in-phase lgkmcnt(0) + phase-end barrier); tile t+2 is staged
// into buf[cur] only in P4. vmcnt(8) at P4-end (in-order retirement) proves
// tile t+1's 8 loads landed before the next iteration reads them.
#define BARX() do { asm volatile("" ::: "memory"); __builtin_amdgcn_s_barrier(); \
                    asm volatile("" ::: "memory"); } while (0)

#define DSA(mh, c) do { \
    const char* _ba = smem + (c) * 65536 + abase; \
    _Pragma("unroll") for (int mf = 0; mf < 4; mf++) \
    _Pragma("unroll") for (int kk = 0; kk < 2; kk++) \
        areg[mf][kk] = *(const short8*)(_ba + ((mh) * 4 + mf) * 2048 + kof[kk]); \
} while (0)

#define DSB(nh, c) do { \
    const char* _bb = smem + (c) * 65536 + bbase; \
    _Pragma("unroll") for (int nf = 0; nf < 2; nf++) \
    _Pragma("unroll") for (int kk = 0; kk < 2; kk++) \
        breg[(nh) * 2 + nf][kk] = *(const short8*)(_bb + ((nh) * 2 + nf) * 2048 + kof[kk]); \
} while (0)

#define MMAQ(mh, nh) do { \
    asm volatile("s_waitcnt lgkmcnt(0)" ::: "memory"); \
    __builtin_amdgcn_sched_barrier(0); \
    __builtin_amdgcn_s_setprio(1); \
    _Pragma("unroll") for (int mf = 0; mf < 4; mf++) \
    _Pragma("unroll") for (int nf = 0; nf < 2; nf++) \
    _Pragma("unroll") for (int kk = 0; kk < 2; kk++) \
        acc[(mh) * 4 + mf][(nh) * 2 + nf] = __builtin_amdgcn_mfma_f32_16x16x32_bf16( \
            areg[mf][kk], breg[(nh) * 2 + nf][kk], acc[(mh) * 4 + mf][(nh) * 2 + nf], 0, 0, 0); \
    __builtin_amdgcn_s_setprio(0); \
} while (0)

// op: 0=A(src ya, rows mrow0)  1=B(src wbp, rows nrow0); half h; K-tile kt
#define STG(op, c, h, kt) do { \
    const u16* _gs = (op) ? wbp : yap; \
    int _tr0 = (op) ? nrow0 : mrow0; \
    _Pragma("unroll") for (int p = 0; p < 2; p++) { \
        int _idx = p * 512 + t; \
        int _row = _idx >> 3; \
        int _gcol = (((_idx & 7) ^ (_row & 7)) << 3); \
        gload_lds16(_gs + (size_t)(_tr0 + (h) * 128 + _row) * 2048 + (kt) * 64 + _gcol, \
                    smem + (c) * 65536 + (op) * 32768 + (h) * 16384 + _idx * 16); \
    } \
} while (0)

__global__ __launch_bounds__(512, 2) void final_gemm256(const u16* __restrict__ yap,
                                                        const u16* __restrict__ wbp,
                                                        const float* __restrict__ b3,
                                                        float* __restrict__ out) {
    extern __shared__ char smem[];
    const int t = threadIdx.x;
    const int lane = t & 63, w = t >> 6;
    const int wm = w >> 2, wn = w & 3;
    const int l15 = lane & 15, l4 = lane >> 4, sx = lane & 7;

    // XCD swizzle: 512 wgs, 8 XCDs -> each XCD owns one 256-col panel
    int bid = blockIdx.x;
    int swz = (bid & 7) * 64 + (bid >> 3);
    int nblk = swz >> 6, mblk = swz & 63;
    const int mrow0 = mblk * 256;
    const int nrow0 = nblk * 256;

    const int abase = wm * 16384 + l15 * 128;
    const int bbase = 32768 + (wn >> 1) * 16384 + ((wn & 1) * 64 + l15) * 128;
    int kof[2];
#pragma unroll
    for (int kk = 0; kk < 2; kk++) kof[kk] = ((kk * 4 + l4) ^ sx) << 4;

    f32x4 acc[8][4];
#pragma unroll
    for (int m = 0; m < 8; m++)
#pragma unroll
        for (int n = 0; n < 4; n++) acc[m][n] = (f32x4){0.f, 0.f, 0.f, 0.f};
    short8 areg[4][2];
    short8 breg[4][2];

    // prologue: tile0 -> buf0, tile1 -> buf1 (16 loads/thread), wait tile0
    STG(0, 0, 0, 0); STG(0, 0, 1, 0); STG(1, 0, 0, 0); STG(1, 0, 1, 0);
    STG(0, 1, 0, 1); STG(0, 1, 1, 1); STG(1, 1, 0, 1); STG(1, 1, 1, 1);
    asm volatile("s_waitcnt vmcnt(8)" ::: "memory");
    BARX();

    for (int it2 = 0; it2 < 16; ++it2) {
#pragma unroll
        for (int c = 0; c < 2; ++c) {
            const int tt = 2 * it2 + c;           // current K-tile index
            const bool st = (tt < 30);            // stage tile tt+2 this iter
            // P1
            DSA(0, c); DSB(0, c);
            BARX(); MMAQ(0, 0); BARX();
            // P2
            DSB(1, c);
            BARX(); MMAQ(0, 1); BARX();
            // P3  (last reads of buf[c]; sealed by lgkmcnt(0)+barrier)
            DSA(1, c);
            BARX(); MMAQ(1, 0); BARX();
            // P4  (stage tile tt+2 into buf[c] — no live readers remain)
            if (st) { STG(0, c, 0, tt + 2); STG(0, c, 1, tt + 2);
                      STG(1, c, 0, tt + 2); STG(1, c, 1, tt + 2); }
            BARX(); MMAQ(1, 1);
            if (st)             asm volatile("s_waitcnt vmcnt(8)" ::: "memory");
            else if (tt == 30)  asm volatile("s_waitcnt vmcnt(0)" ::: "memory");
            BARX();
        }
    }

    // epilogue: bias + fp32 store
#pragma unroll
    for (int m = 0; m < 8; m++)
#pragma unroll
        for (int n = 0; n < 4; n++) {
            int col = nrow0 + wn * 64 + n * 16 + l15;
            float bias = b3[col];
            int row = mrow0 + wm * 128 + m * 16 + l4 * 4;
#pragma unroll
            for (int j = 0; j < 4; j++)
                out[(size_t)(row + j) * 2048 + col] = acc[m][n][j] + bias;
        }
}

// ---------------------------------------------------------------------------
extern "C" void kernel_launch(void* const* d_in, const int* in_sizes, int n_in,
                              void* d_out, int out_size, void* d_ws, size_t ws_size,
                              hipStream_t stream) {
    const float* x   = (const float*)d_in[0];
    const float* sw  = (const float*)d_in[1];
    const float* swb = (const float*)d_in[2];
    const float* w1  = (const float*)d_in[3];
    const float* b1  = (const float*)d_in[4];
    const float* w2  = (const float*)d_in[5];
    const float* b2  = (const float*)d_in[6];
    const float* w3  = (const float*)d_in[7];
    const float* b3  = (const float*)d_in[8];
    float* out = (float*)d_out;

    char* ws = (char*)d_ws;
    float* part = (float*)(ws + 0);                 // 128 KB
    float* gate = (float*)(ws + 131072);            // 64 B
    int*   idx  = (int*)(ws + 131136);              // 64 B
    float* bc   = (float*)(ws + 131200);            // 4 KB
    u16*   w1b  = (u16*)(ws + 262144);              // 256 KB (swizzled)
    u16*   w2b  = (u16*)(ws + 524288);              // 256 KB
    u16*   w3b  = (u16*)(ws + 786432);              // 8 MB
    u16*   y    = (u16*)(ws + 9175040);             // 64 MB
    u16*   xb   = (u16*)(ws + 76283904);            // 64 MB (swizzled bf16 x)
    const size_t need_xb = 143392768;
    const bool xbmode = ws_size >= need_xb;

    hipFuncSetAttribute((const void*)final_gemm256,
                        hipFuncAttributeMaxDynamicSharedMemorySize, 131072);

    if (xbmode)
        hipLaunchKernelGGL((router_partial<1>), dim3(NCHUNK), dim3(256), 0, stream, x, sw, part, xb);
    else
        hipLaunchKernelGGL((router_partial<0>), dim3(NCHUNK), dim3(256), 0, stream, x, sw, part, xb);
    hipLaunchKernelGGL(router_finish, dim3(1), dim3(128), 0, stream, part, swb, b2, gate, idx, bc);
    hipLaunchKernelGGL(convert_w12, dim3(256), dim3(256), 0, stream, w1, w2, w1b, w2b);
    hipLaunchKernelGGL(convert_w3, dim3(D_ * D_ / 1024), dim3(256), 0, stream, w3, w3b);
    if (xbmode)
        hipLaunchKernelGGL((mlp_kernel<1>), dim3(64, 8), dim3(512), 0, stream,
                           (const void*)xb, w1b, w2b, b1, gate, idx, bc, y);
    else
        hipLaunchKernelGGL((mlp_kernel<0>), dim3(64, 8), dim3(512), 0, stream,
                           (const void*)x, w1b, w2b, b1, gate, idx, bc, y);
    hipLaunchKernelGGL(final_gemm256, dim3(512), dim3(512), 131072, stream,
                       y, w3b, b3, out);
}

// Round 5
// 333.905 us; speedup vs baseline: 1.4891x; 1.0405x over previous
//
#include <hip/hip_runtime.h>
#include <math.h>

typedef unsigned short u16;
typedef unsigned int u32;
typedef __attribute__((ext_vector_type(8))) short short8;
typedef __attribute__((ext_vector_type(4))) float f32x4;
typedef __attribute__((ext_vector_type(4))) unsigned short ushort4v;

#define B_ 8
#define S_ 2048
#define D_ 2048
#define H_ 16
#define RLEN 4194304   // S_*D_ elems per batch sample
#define NCHUNK 512

static __device__ __forceinline__ u16 f2bf(float f) {
    union { float f; u32 u; } v; v.f = f;
    u32 r = v.u + 0x7fffu + ((v.u >> 16) & 1u);
    return (u16)(r >> 16);
}
static __device__ __forceinline__ float bf2f(u16 u) {
    union { u32 u; float f; } v; v.u = ((u32)u) << 16;
    return v.f;
}

typedef const __attribute__((address_space(1))) u32* gas1_t;
typedef __attribute__((address_space(3))) u32* las3_t;
static __device__ __forceinline__ void gload_lds16(const void* g, void* l) {
    __builtin_amdgcn_global_load_lds((gas1_t)g, (las3_t)l, 16, 0, 0);
}

// ---------------- Kernel 1: router partial dots (+ fused x->bf16 swizzled) --
template<int XB>
__global__ __launch_bounds__(256) void router_partial(const float* __restrict__ x,
                                                      const float* __restrict__ sw,
                                                      float* __restrict__ part,
                                                      u16* __restrict__ xb) {
    int c = blockIdx.x;
    int t = threadIdx.x;
    const int chunk = RLEN / NCHUNK;        // 8192
    int base = c * chunk;
    float acc[8][8];
#pragma unroll
    for (int b = 0; b < 8; b++)
#pragma unroll
        for (int e = 0; e < 8; e++) acc[b][e] = 0.f;

    for (int it = 0; it < chunk / (256 * 4); ++it) {   // 8 iterations
        int i = base + (it * 256 + t) * 4;
        float4 xv[8], sv[8];
#pragma unroll
        for (int b = 0; b < 8; b++) xv[b] = *(const float4*)&x[(size_t)b * RLEN + i];
#pragma unroll
        for (int e = 0; e < 8; e++) sv[e] = *(const float4*)&sw[(size_t)e * RLEN + i];
        if (XB) {
            int row = i >> 7, col = i & 127;
            int scol = (((col >> 3) ^ (row & 7)) << 3) | (col & 7);
#pragma unroll
            for (int b = 0; b < 8; b++) {
                ushort4v u;
                u.x = f2bf(xv[b].x); u.y = f2bf(xv[b].y);
                u.z = f2bf(xv[b].z); u.w = f2bf(xv[b].w);
                *(ushort4v*)&xb[(size_t)b * RLEN + (size_t)row * 128 + scol] = u;
            }
        }
#pragma unroll
        for (int b = 0; b < 8; b++)
#pragma unroll
            for (int e = 0; e < 8; e++)
                acc[b][e] += xv[b].x * sv[e].x + xv[b].y * sv[e].y +
                             xv[b].z * sv[e].z + xv[b].w * sv[e].w;
    }

    __shared__ float red[4][64];
    int lane = t & 63, wv = t >> 6;
#pragma unroll
    for (int q = 0; q < 64; q++) {
        float v = acc[q >> 3][q & 7];
#pragma unroll
        for (int m = 32; m >= 1; m >>= 1) v += __shfl_xor(v, m, 64);
        if (lane == 0) red[wv][q] = v;
    }
    __syncthreads();
    if (t < 64) {
        float s = red[0][t] + red[1][t] + red[2][t] + red[3][t];
        part[(size_t)t * NCHUNK + c] = s;
    }
}

// ---------------- Kernel 2: reduce + softmax + top-2 + combined b2 bias ----
__global__ __launch_bounds__(128) void router_finish(const float* __restrict__ part,
                                                     const float* __restrict__ swb,
                                                     const float* __restrict__ b2,
                                                     float* __restrict__ gate,
                                                     int* __restrict__ idx,
                                                     float* __restrict__ bc) {
    int t = threadIdx.x;
    __shared__ float lg[64];
    __shared__ float sg[16];
    __shared__ int   si[16];
    if (t < 64) {
        float s = 0.f;
        for (int c = 0; c < NCHUNK; c++) s += part[(size_t)t * NCHUNK + c];
        lg[t] = s + swb[t & 7];
    }
    __syncthreads();
    if (t < 8) {
        int b = t;
        float m = -1e30f;
        for (int e = 0; e < 8; e++) m = fmaxf(m, lg[b * 8 + e]);
        float p[8]; float sum = 0.f;
        for (int e = 0; e < 8; e++) { p[e] = expf(lg[b * 8 + e] - m); sum += p[e]; }
        for (int e = 0; e < 8; e++) p[e] /= sum;
        int i1 = 0; float v1 = p[0];
        for (int e = 1; e < 8; e++) if (p[e] > v1) { v1 = p[e]; i1 = e; }
        int i2 = -1; float v2 = -1.f;
        for (int e = 0; e < 8; e++) if (e != i1 && p[e] > v2) { v2 = p[e]; i2 = e; }
        gate[b * 2 + 0] = v1; gate[b * 2 + 1] = v2;
        idx[b * 2 + 0] = i1;  idx[b * 2 + 1] = i2;
        sg[b * 2] = v1; sg[b * 2 + 1] = v2;
        si[b * 2] = i1; si[b * 2 + 1] = i2;
    }
    __syncthreads();
    for (int b = 0; b < 8; b++)
        bc[b * 128 + t] = sg[b * 2] * b2[si[b * 2] * 128 + t] +
                          sg[b * 2 + 1] * b2[si[b * 2 + 1] * 128 + t];
}

// ---------------- Kernel 3a: w1/w2 -> bf16 (w1 swizzled) -------------------
__global__ __launch_bounds__(256) void convert_w12(const float* __restrict__ w1,
                                                   const float* __restrict__ w2,
                                                   u16* __restrict__ w1b,
                                                   u16* __restrict__ w2b) {
    int i4 = (blockIdx.x * 256 + threadIdx.x) * 4;
    if (i4 < 131072) {
        int k = i4 & 127, f = (i4 >> 7) & 127;
        float4 v = *(const float4*)&w1[i4];
        int sc = ((((k >> 3) ^ (f & 7)) << 3) | (k & 7));
        ushort4v u;
        u.x = f2bf(v.x); u.y = f2bf(v.y); u.z = f2bf(v.z); u.w = f2bf(v.w);
        *(ushort4v*)&w1b[(i4 & ~127) + sc] = u;
    } else {
        int j = i4 - 131072;
        float4 v = *(const float4*)&w2[j];
        ushort4v u;
        u.x = f2bf(v.x); u.y = f2bf(v.y); u.z = f2bf(v.z); u.w = f2bf(v.w);
        *(ushort4v*)&w2b[j] = u;
    }
}

// ---------------- Kernel 3b: w3 -> bf16 ------------------------------------
__global__ __launch_bounds__(256) void convert_w3(const float* __restrict__ w3,
                                                  u16* __restrict__ w3b) {
    size_t i = ((size_t)blockIdx.x * 256 + threadIdx.x) * 4;
    float4 v = *(const float4*)&w3[i];
    u16* d = &w3b[i];
    d[0] = f2bf(v.x); d[1] = f2bf(v.y); d[2] = f2bf(v.z); d[3] = f2bf(v.w);
}

// ---------------- Kernel 4: expert MLP, weights resident, 512-row blocks ---
template<int XB>
__global__ __launch_bounds__(512, 2) void mlp_kernel(const void* __restrict__ xsrc_,
                                                     const u16* __restrict__ w1b,
                                                     const u16* __restrict__ w2b,
                                                     const float* __restrict__ b1,
                                                     const float* __restrict__ gate,
                                                     const int* __restrict__ idx,
                                                     const float* __restrict__ bc,
                                                     u16* __restrict__ y) {
    __shared__ __align__(16) u16 w1s[256 * 128];   // 64 KB
    __shared__ __align__(16) u16 xs[2][64 * 128];  // 32 KB (dbuf)
    __shared__ __align__(16) u16 hb[64 * 256];     // 32 KB
    const int t = threadIdx.x, lane = t & 63, w = t >> 6;
    const int wr = w >> 2, wq = w & 3;
    const int b = blockIdx.y, grp = blockIdx.x;
    const size_t xbase = (size_t)b * RLEN;
    const size_t gbase = xbase + (size_t)grp * 65536;
    const int e0 = idx[b * 2], e1 = idx[b * 2 + 1];
    const int slot = wq >> 1;
    const float gw = gate[b * 2 + slot];
    const float* b1p = b1 + (slot ? e1 : e0) * 128;

    float b1v[4];
#pragma unroll
    for (int nt = 0; nt < 4; nt++)
        b1v[nt] = b1p[(wq & 1) * 64 + nt * 16 + (lane & 15)];
    float bcv[2];
#pragma unroll
    for (int n = 0; n < 2; n++)
        bcv[n] = bc[b * 128 + wq * 32 + n * 16 + (lane & 15)];

    short8 w2f[2][8];
#pragma unroll
    for (int n = 0; n < 2; n++) {
        int d = wq * 32 + n * 16 + (lane & 15);
#pragma unroll
        for (int kb = 0; kb < 8; kb++) {
            int e = (kb >= 4) ? e1 : e0;
            int f = (kb & 3) * 32 + (lane >> 4) * 8;
            w2f[n][kb] = *(const short8*)&w2b[((size_t)(e * 128 + d)) * 128 + f];
        }
    }

#pragma unroll
    for (int p = 0; p < 8; p++) {
        int elem = p * 4096 + t * 8;
        int frow = elem >> 7, col = elem & 127;
        int e = (frow >= 128) ? e1 : e0;
        gload_lds16(w1b + ((size_t)(e * 128 + (frow & 127))) * 128 + col,
                    (char*)w1s + elem * 2);
    }
    if (XB) {
        const u16* xbp = (const u16*)xsrc_;
#pragma unroll
        for (int p = 0; p < 2; p++) {
            int elem = p * 4096 + t * 8;
            gload_lds16(xbp + gbase + elem, (char*)&xs[0][0] + elem * 2);
        }
        asm volatile("s_waitcnt vmcnt(0)" ::: "memory");
    } else {
        const float* xf = (const float*)xsrc_;
#pragma unroll
        for (int p = 0; p < 4; p++) {
            int elem = p * 2048 + t * 4;
            int row = elem >> 7, col = elem & 127;
            float4 v = *(const float4*)&xf[gbase + elem];
            ushort4v u;
            u.x = f2bf(v.x); u.y = f2bf(v.y); u.z = f2bf(v.z); u.w = f2bf(v.w);
            *(ushort4v*)((char*)&xs[0][0] + row * 256 +
                         (((col >> 3) ^ (row & 7)) << 4) + (col & 7) * 2) = u;
        }
        asm volatile("s_waitcnt vmcnt(0) lgkmcnt(0)" ::: "memory");
    }
    __builtin_amdgcn_s_barrier();

    for (int tt = 0; tt < 8; ++tt) {
        const u16* xc = &xs[tt & 1][0];
        u16* xn = &xs[(tt + 1) & 1][0];
        float4 pre[4];
        if (tt < 7) {
            if (XB) {
                const u16* xbp = (const u16*)xsrc_;
#pragma unroll
                for (int p = 0; p < 2; p++) {
                    int elem = p * 4096 + t * 8;
                    gload_lds16(xbp + gbase + (tt + 1) * 8192 + elem,
                                (char*)xn + elem * 2);
                }
            } else {
                const float* xf = (const float*)xsrc_;
#pragma unroll
                for (int p = 0; p < 4; p++) {
                    int elem = p * 2048 + t * 4;
                    pre[p] = *(const float4*)&xf[gbase + (tt + 1) * 8192 + elem];
                }
            }
        }

        f32x4 acc1[2][4];
#pragma unroll
        for (int mt = 0; mt < 2; mt++)
#pragma unroll
            for (int nt = 0; nt < 4; nt++) acc1[mt][nt] = (f32x4){0.f, 0.f, 0.f, 0.f};
#pragma unroll
        for (int kb = 0; kb < 4; kb++) {
            int kg = kb * 4 + (lane >> 4);
            int r0 = wr * 32 + (lane & 15);
            int r1 = r0 + 16;
            short8 a0 = *(const short8*)&xc[r0 * 128 + ((kg ^ (r0 & 7)) << 3)];
            short8 a1 = *(const short8*)&xc[r1 * 128 + ((kg ^ (r1 & 7)) << 3)];
#pragma unroll
            for (int nt = 0; nt < 4; nt++) {
                int fr = wq * 64 + nt * 16 + (lane & 15);
                short8 bb = *(const short8*)&w1s[fr * 128 + ((kg ^ (fr & 7)) << 3)];
                acc1[0][nt] = __builtin_amdgcn_mfma_f32_16x16x32_bf16(a0, bb, acc1[0][nt], 0, 0, 0);
                acc1[1][nt] = __builtin_amdgcn_mfma_f32_16x16x32_bf16(a1, bb, acc1[1][nt], 0, 0, 0);
            }
        }

#pragma unroll
        for (int mt = 0; mt < 2; mt++)
#pragma unroll
            for (int nt = 0; nt < 4; nt++) {
                int fcol = wq * 64 + nt * 16 + (lane & 15);
#pragma unroll
                for (int j = 0; j < 4; j++) {
                    int row = wr * 32 + mt * 16 + (lane >> 4) * 4 + j;
                    float v = acc1[mt][nt][j] + b1v[nt];
                    v = 0.5f * v * (1.0f + erff(v * 0.70710678118654752f)) * gw;
                    hb[row * 256 + ((((fcol >> 3) ^ (row & 7)) << 3) | (fcol & 7))] = f2bf(v);
                }
            }
        asm volatile("s_waitcnt lgkmcnt(0)" ::: "memory");
        __builtin_amdgcn_s_barrier();

        if (!XB && tt < 7) {
#pragma unroll
            for (int p = 0; p < 4; p++) {
                int elem = p * 2048 + t * 4;
                int row = elem >> 7, col = elem & 127;
                ushort4v u;
                u.x = f2bf(pre[p].x); u.y = f2bf(pre[p].y);
                u.z = f2bf(pre[p].z); u.w = f2bf(pre[p].w);
                *(ushort4v*)((char*)xn + row * 256 +
                             (((col >> 3) ^ (row & 7)) << 4) + (col & 7) * 2) = u;
            }
        }

        f32x4 acc2[2][2];
#pragma unroll
        for (int mt = 0; mt < 2; mt++)
#pragma unroll
            for (int n = 0; n < 2; n++) acc2[mt][n] = (f32x4){0.f, 0.f, 0.f, 0.f};
#pragma unroll
        for (int kb = 0; kb < 8; kb++) {
            int fg = kb * 4 + (lane >> 4);
            int r0 = wr * 32 + (lane & 15);
            int r1 = r0 + 16;
            short8 a0 = *(const short8*)&hb[r0 * 256 + ((fg ^ (r0 & 7)) << 3)];
            short8 a1 = *(const short8*)&hb[r1 * 256 + ((fg ^ (r1 & 7)) << 3)];
            acc2[0][0] = __builtin_amdgcn_mfma_f32_16x16x32_bf16(a0, w2f[0][kb], acc2[0][0], 0, 0, 0);
            acc2[0][1] = __builtin_amdgcn_mfma_f32_16x16x32_bf16(a0, w2f[1][kb], acc2[0][1], 0, 0, 0);
            acc2[1][0] = __builtin_amdgcn_mfma_f32_16x16x32_bf16(a1, w2f[0][kb], acc2[1][0], 0, 0, 0);
            acc2[1][1] = __builtin_amdgcn_mfma_f32_16x16x32_bf16(a1, w2f[1][kb], acc2[1][1], 0, 0, 0);
        }

        u16* yb = y + xbase + (size_t)grp * 65536 + tt * 8192;
#pragma unroll
        for (int mt = 0; mt < 2; mt++)
#pragma unroll
            for (int n = 0; n < 2; n++) {
                int d = wq * 32 + n * 16 + (lane & 15);
#pragma unroll
                for (int j = 0; j < 4; j++) {
                    int row = wr * 32 + mt * 16 + (lane >> 4) * 4 + j;
                    float xr = bf2f(xc[row * 128 + ((((d >> 3) ^ (row & 7)) << 3) | (d & 7))]);
                    yb[row * 128 + d] = f2bf(acc2[mt][n][j] + bcv[n] + xr);
                }
            }
        asm volatile("s_waitcnt lgkmcnt(0)" ::: "memory");
        if (XB && tt < 7) asm volatile("s_waitcnt vmcnt(16)" ::: "memory");
        __builtin_amdgcn_s_barrier();
    }
}

// ---------------- Kernel 5: out = y @ w3^T + b3, 256^2 low-barrier ---------
// BM=BN=256, BK=64, 8 waves (2Mx4N), 128KB dynamic LDS (2 dbuf x A/B 32KB).
// 2 barriers per K-tile: quadrant MFMAs run barrier-free (per-wave lgkmcnt
// drains own ds_reads; waves drift anti-phase -> LDS reads of one wave
// overlap MFMA of another). Hazards: (i) BARX after last buf[c] ds_read
// (drained) before STG into buf[c]; (ii) vmcnt(8)+BARX proves tile tt+1's
// loads landed block-wide before reading buf[c^1].
#define BARX() do { asm volatile("" ::: "memory"); __builtin_amdgcn_s_barrier(); \
                    asm volatile("" ::: "memory"); } while (0)

#define DSA(mh, c) do { \
    const char* _ba = smem + (c) * 65536 + abase; \
    _Pragma("unroll") for (int mf = 0; mf < 4; mf++) \
    _Pragma("unroll") for (int kk = 0; kk < 2; kk++) \
        areg[mf][kk] = *(const short8*)(_ba + ((mh) * 4 + mf) * 2048 + kof[kk]); \
} while (0)

#define DSB(nh, c) do { \
    const char* _bb = smem + (c) * 65536 + bbase; \
    _Pragma("unroll") for (int nf = 0; nf < 2; nf++) \
    _Pragma("unroll") for (int kk = 0; kk < 2; kk++) \
        breg[(nh) * 2 + nf][kk] = *(const short8*)(_bb + ((nh) * 2 + nf) * 2048 + kof[kk]); \
} while (0)

#define MMAQ(mh, nh) do { \
    asm volatile("s_waitcnt lgkmcnt(0)" ::: "memory"); \
    __builtin_amdgcn_sched_barrier(0); \
    __builtin_amdgcn_s_setprio(1); \
    _Pragma("unroll") for (int mf = 0; mf < 4; mf++) \
    _Pragma("unroll") for (int nf = 0; nf < 2; nf++) \
    _Pragma("unroll") for (int kk = 0; kk < 2; kk++) \
        acc[(mh) * 4 + mf][(nh) * 2 + nf] = __builtin_amdgcn_mfma_f32_16x16x32_bf16( \
            areg[mf][kk], breg[(nh) * 2 + nf][kk], acc[(mh) * 4 + mf][(nh) * 2 + nf], 0, 0, 0); \
    __builtin_amdgcn_s_setprio(0); \
} while (0)

// op: 0=A(src ya, rows mrow0)  1=B(src wbp, rows nrow0); half h; K-tile kt
#define STG(op, c, h, kt) do { \
    const u16* _gs = (op) ? wbp : yap; \
    int _tr0 = (op) ? nrow0 : mrow0; \
    _Pragma("unroll") for (int p = 0; p < 2; p++) { \
        int _idx = p * 512 + t; \
        int _row = _idx >> 3; \
        int _gcol = (((_idx & 7) ^ (_row & 7)) << 3); \
        gload_lds16(_gs + (size_t)(_tr0 + (h) * 128 + _row) * 2048 + (kt) * 64 + _gcol, \
                    smem + (c) * 65536 + (op) * 32768 + (h) * 16384 + _idx * 16); \
    } \
} while (0)

__global__ __launch_bounds__(512, 2) void final_gemm256(const u16* __restrict__ yap,
                                                        const u16* __restrict__ wbp,
                                                        const float* __restrict__ b3,
                                                        float* __restrict__ out) {
    extern __shared__ char smem[];
    const int t = threadIdx.x;
    const int lane = t & 63, w = t >> 6;
    const int wm = w >> 2, wn = w & 3;
    const int l15 = lane & 15, l4 = lane >> 4, sx = lane & 7;

    // XCD swizzle: 512 wgs, 8 XCDs -> each XCD owns one 256-col panel
    int bid = blockIdx.x;
    int swz = (bid & 7) * 64 + (bid >> 3);
    int nblk = swz >> 6, mblk = swz & 63;
    const int mrow0 = mblk * 256;
    const int nrow0 = nblk * 256;

    const int abase = wm * 16384 + l15 * 128;
    const int bbase = 32768 + (wn >> 1) * 16384 + ((wn & 1) * 64 + l15) * 128;
    int kof[2];
#pragma unroll
    for (int kk = 0; kk < 2; kk++) kof[kk] = ((kk * 4 + l4) ^ sx) << 4;

    f32x4 acc[8][4];
#pragma unroll
    for (int m = 0; m < 8; m++)
#pragma unroll
        for (int n = 0; n < 4; n++) acc[m][n] = (f32x4){0.f, 0.f, 0.f, 0.f};
    short8 areg[4][2];
    short8 breg[4][2];

    // prologue: tile0 -> buf0, tile1 -> buf1 (16 loads/thread), wait tile0
    STG(0, 0, 0, 0); STG(0, 0, 1, 0); STG(1, 0, 0, 0); STG(1, 0, 1, 0);
    STG(0, 1, 0, 1); STG(0, 1, 1, 1); STG(1, 1, 0, 1); STG(1, 1, 1, 1);
    asm volatile("s_waitcnt vmcnt(8)" ::: "memory");
    BARX();

    for (int it2 = 0; it2 < 16; ++it2) {
#pragma unroll
        for (int c = 0; c < 2; ++c) {
            const int tt = 2 * it2 + c;           // current K-tile index
            const bool st = (tt < 30);            // stage tile tt+2 this iter
            // barrier-free quadrant pipeline (per-wave lgkm drains only)
            DSA(0, c); DSB(0, c);
            MMAQ(0, 0);
            DSB(1, c);
            MMAQ(0, 1);
            DSA(1, c);                            // last buf[c] ds_read
            MMAQ(1, 0);
            BARX();                               // (i) all waves done reading buf[c]
            if (st) { STG(0, c, 0, tt + 2); STG(0, c, 1, tt + 2);
                      STG(1, c, 0, tt + 2); STG(1, c, 1, tt + 2); }
            MMAQ(1, 1);                           // operands already in regs
            if (st)             asm volatile("s_waitcnt vmcnt(8)" ::: "memory");
            else if (tt == 30)  asm volatile("s_waitcnt vmcnt(0)" ::: "memory");
            BARX();                               // (ii) tile tt+1 visible block-wide
        }
    }

    // epilogue: bias + fp32 store
#pragma unroll
    for (int m = 0; m < 8; m++)
#pragma unroll
        for (int n = 0; n < 4; n++) {
            int col = nrow0 + wn * 64 + n * 16 + l15;
            float bias = b3[col];
            int row = mrow0 + wm * 128 + m * 16 + l4 * 4;
#pragma unroll
            for (int j = 0; j < 4; j++)
                out[(size_t)(row + j) * 2048 + col] = acc[m][n][j] + bias;
        }
}

// ---------------------------------------------------------------------------
extern "C" void kernel_launch(void* const* d_in, const int* in_sizes, int n_in,
                              void* d_out, int out_size, void* d_ws, size_t ws_size,
                              hipStream_t stream) {
    const float* x   = (const float*)d_in[0];
    const float* sw  = (const float*)d_in[1];
    const float* swb = (const float*)d_in[2];
    const float* w1  = (const float*)d_in[3];
    const float* b1  = (const float*)d_in[4];
    const float* w2  = (const float*)d_in[5];
    const float* b2  = (const float*)d_in[6];
    const float* w3  = (const float*)d_in[7];
    const float* b3  = (const float*)d_in[8];
    float* out = (float*)d_out;

    char* ws = (char*)d_ws;
    float* part = (float*)(ws + 0);                 // 128 KB
    float* gate = (float*)(ws + 131072);            // 64 B
    int*   idx  = (int*)(ws + 131136);              // 64 B
    float* bc   = (float*)(ws + 131200);            // 4 KB
    u16*   w1b  = (u16*)(ws + 262144);              // 256 KB (swizzled)
    u16*   w2b  = (u16*)(ws + 524288);              // 256 KB
    u16*   w3b  = (u16*)(ws + 786432);              // 8 MB
    u16*   y    = (u16*)(ws + 9175040);             // 64 MB
    u16*   xb   = (u16*)(ws + 76283904);            // 64 MB (swizzled bf16 x)
    const size_t need_xb = 143392768;
    const bool xbmode = ws_size >= need_xb;

    hipFuncSetAttribute((const void*)final_gemm256,
                        hipFuncAttributeMaxDynamicSharedMemorySize, 131072);

    if (xbmode)
        hipLaunchKernelGGL((router_partial<1>), dim3(NCHUNK), dim3(256), 0, stream, x, sw, part, xb);
    else
        hipLaunchKernelGGL((router_partial<0>), dim3(NCHUNK), dim3(256), 0, stream, x, sw, part, xb);
    hipLaunchKernelGGL(router_finish, dim3(1), dim3(128), 0, stream, part, swb, b2, gate, idx, bc);
    hipLaunchKernelGGL(convert_w12, dim3(256), dim3(256), 0, stream, w1, w2, w1b, w2b);
    hipLaunchKernelGGL(convert_w3, dim3(D_ * D_ / 1024), dim3(256), 0, stream, w3, w3b);
    if (xbmode)
        hipLaunchKernelGGL((mlp_kernel<1>), dim3(64, 8), dim3(512), 0, stream,
                           (const void*)xb, w1b, w2b, b1, gate, idx, bc, y);
    else
        hipLaunchKernelGGL((mlp_kernel<0>), dim3(64, 8), dim3(512), 0, stream,
                           (const void*)x, w1b, w2b, b1, gate, idx, bc, y);
    hipLaunchKernelGGL(final_gemm256, dim3(512), dim3(512), 131072, stream,
                       y, w3b, b3, out);
}